// Round 20
// baseline (215.566 us; speedup 1.0000x reference)
//
#include <hip/hip_runtime.h>
#include <hip/hip_bf16.h>

#define NN 2560        // nodes
#define NE 163840      // edges
#define NH 4           // heads
#define NC 128         // channels per head
#define NF 512         // NH*NC
#define OUTE 40
#define CSTR 256       // fixed CSR stride per node; deg>CSTR -> overflow list

typedef short bf16x8 __attribute__((ext_vector_type(8)));
typedef float f32x4 __attribute__((ext_vector_type(4)));

__device__ inline ushort f2bf(float f) {
    uint u = __float_as_uint(f);
    uint r = u + 0x7FFF + ((u >> 16) & 1);   // round-to-nearest-even
    return (ushort)(r >> 16);
}
__device__ inline float bflo(uint v) { return __uint_as_float(v << 16); }
__device__ inline float bfhi(uint v) { return __uint_as_float(v & 0xFFFF0000u); }
__device__ inline float bf2f(ushort u) { return __uint_as_float(((uint)u) << 16); }

// ---------------- kernel 1: CSR fill (single-pass) + dote/WfcT/W2T + GEMM1+att
// blocks 0..639: CSR fill; 640..641: dote; 642..737: WfcT; 738..801: W2T;
// 802..1121: gemm1 + node-att for 8 nodes each (W1 L2 traffic halved vs 4).
__global__ __launch_bounds__(256) void k_csr_gemm1(const int* __restrict__ ei,
        const float* __restrict__ pos, int* __restrict__ deg,
        int2* __restrict__ csrp, int* __restrict__ ovf_cnt, int4* __restrict__ ovf,
        const float* __restrict__ We1, const float* __restrict__ ae1,
        const float* __restrict__ We2, const float* __restrict__ ae2,
        float* __restrict__ dote,
        const float* __restrict__ Wfc, ushort* __restrict__ WfcT,
        const float* __restrict__ W2, ushort* __restrict__ W2T,
        const float* __restrict__ x, const float* __restrict__ W1,
        const float* __restrict__ atts, const float* __restrict__ attd,
        ushort* __restrict__ hb, float* __restrict__ as_, float* __restrict__ ad_) {
    __shared__ ushort tile[64][72];
    __shared__ float s_x[8][32];
    __shared__ float4 s_red[4][8];     // [wave][node]
    int b = blockIdx.x;
    if (b < 640) {
        int e = b * 256 + threadIdx.x;
        int s = ei[e], d = ei[NE + e];
        float dx = pos[2 * s] - pos[2 * d];
        float dy = pos[2 * s + 1] - pos[2 * d + 1];
        float w = 1.0f / (sqrtf(dx * dx + dy * dy) + 1e-6f);
        int r = atomicAdd(&deg[d], 1);     // slot + degree in one pass
        if (r < CSTR) {
            csrp[(d << 8) + r] = make_int2(s, __float_as_int(w));
        } else {                            // pathological deg > CSTR: exact fallback
            int i = atomicAdd(ovf_cnt, 1);
            ovf[i] = make_int4(d, s, __float_as_int(w), 0);
        }
        return;
    }
    if (b < 642) {
        int t = threadIdx.x;
        const float* W = (b == 641) ? We2 : We1;
        const float* A = (b == 641) ? ae2 : ae1;
        int w = t >> 6, l = t & 63;
        float p = W[w * 128 + l] * A[w * 128 + l] + W[w * 128 + 64 + l] * A[w * 128 + 64 + l];
#pragma unroll
        for (int o = 32; o > 0; o >>= 1) p += __shfl_down(p, o);
        if (l == 0) dote[(b - 640) * 4 + w] = p;
        return;
    }
    if (b < 738) {
        int idx = (b - 642) * 256 + threadIdx.x;    // j*512 + k
        int j = idx >> 9, k = idx & 511;
        WfcT[idx] = (j < OUTE) ? f2bf(Wfc[k * OUTE + j]) : (ushort)0;
        return;
    }
    if (b < 802) {
        int id = b - 738;
        int n0 = (id & 7) * 64, k0 = (id >> 3) * 64;
        int t = threadIdx.x;
        int r = t >> 2, cseg = (t & 3) * 16;
#pragma unroll
        for (int c = 0; c < 16; c += 4) {
            float4 v = *(const float4*)&W2[(k0 + r) * 512 + n0 + cseg + c];
            tile[cseg + c + 0][r] = f2bf(v.x);
            tile[cseg + c + 1][r] = f2bf(v.y);
            tile[cseg + c + 2][r] = f2bf(v.z);
            tile[cseg + c + 3][r] = f2bf(v.w);
        }
        __syncthreads();
        *(uint4*)&W2T[(n0 + r) * 512 + k0 + cseg]     = *(uint4*)&tile[r][cseg];
        *(uint4*)&W2T[(n0 + r) * 512 + k0 + cseg + 8] = *(uint4*)&tile[r][cseg + 8];
        return;
    }
    int n0 = (b - 802) * 8, t = threadIdx.x;
    if (t < 256) s_x[t >> 5][t & 31] = x[n0 * 32 + t];
    __syncthreads();
    float a0[8], a1[8];
#pragma unroll
    for (int nn = 0; nn < 8; nn++) { a0[nn] = 0.f; a1[nn] = 0.f; }
#pragma unroll
    for (int k = 0; k < 32; k++) {
        float w0 = W1[k * 512 + t];
        float w1 = W1[k * 512 + t + 256];
#pragma unroll
        for (int nn = 0; nn < 8; nn++) {
            a0[nn] += s_x[nn][k] * w0;
            a1[nn] += s_x[nn][k] * w1;
        }
    }
    float sa0 = atts[t], sa1 = atts[t + 256];
    float da0 = attd[t], da1 = attd[t + 256];
    int w = t >> 6, lane = t & 63;
#pragma unroll
    for (int nn = 0; nn < 8; nn++) {
        hb[(n0 + nn) * 512 + t] = f2bf(a0[nn]);
        hb[(n0 + nn) * 512 + t + 256] = f2bf(a1[nn]);
        float ps0 = a0[nn] * sa0, pd0 = a0[nn] * da0;
        float ps1 = a1[nn] * sa1, pd1 = a1[nn] * da1;
#pragma unroll
        for (int o = 32; o > 0; o >>= 1) {
            ps0 += __shfl_xor(ps0, o); pd0 += __shfl_xor(pd0, o);
            ps1 += __shfl_xor(ps1, o); pd1 += __shfl_xor(pd1, o);
        }
        if (lane == 0) s_red[w][nn] = make_float4(ps0, pd0, ps1, pd1);
    }
    __syncthreads();
    if (t < 8) {
        int nn = t, n = n0 + nn;
        float4 r0 = s_red[0][nn], r1 = s_red[1][nn], r2 = s_red[2][nn], r3 = s_red[3][nn];
        as_[n * 4 + 0] = r0.x + r1.x; as_[n * 4 + 1] = r2.x + r3.x;
        as_[n * 4 + 2] = r0.z + r1.z; as_[n * 4 + 3] = r2.z + r3.z;
        ad_[n * 4 + 0] = r0.y + r1.y; ad_[n * 4 + 1] = r2.y + r3.y;
        ad_[n * 4 + 2] = r0.w + r1.w; ad_[n * 4 + 3] = r2.w + r3.w;
    }
}

// ---------------- kernel 2: softmax+agg, wave = (node, head-pair) ---------
// Zero LDS, zero barriers (R15 structure). Output bf16 (t1b).
__global__ __launch_bounds__(256) void k_edge_agg(const int* __restrict__ deg_,
        const int2* __restrict__ csrp, const int* __restrict__ ovf_cnt,
        const int4* __restrict__ ovf, const float* __restrict__ as_,
        const float* __restrict__ ad_, const float* __restrict__ dote,
        const ushort* __restrict__ hb, const float* __restrict__ bias,
        ushort* __restrict__ outb) {
    int w = threadIdx.x >> 6, lane = threadIdx.x & 63;
    int n = blockIdx.x * 2 + (w >> 1);
    int hp = w & 1;                     // heads 2hp, 2hp+1
    int h0 = 2 * hp;
    int beg = n << 8;
    int degn = deg_[n];
    int dmain = min(degn, CSTR);
    float ad0 = ad_[n * 4 + h0], ad1 = ad_[n * 4 + h0 + 1];
    float d0 = dote[h0], d1 = dote[h0 + 1];
    // ---- phase A: softmax for both heads in registers ----
    float La0 = -1e30f, La1 = -1e30f, Lb0 = -1e30f, Lb1 = -1e30f;
    int off0 = 0, off1 = 0;
    if (lane < dmain) {
        int2 p = csrp[beg + lane];
        off0 = p.x * NF;
        float2 a = *(const float2*)&as_[p.x * 4 + h0];
        float ww = __int_as_float(p.y);
        float v0 = a.x + ad0 + ww * d0; La0 = v0 > 0.f ? v0 : 0.2f * v0;
        float v1 = a.y + ad1 + ww * d1; La1 = v1 > 0.f ? v1 : 0.2f * v1;
    }
    if (lane + 64 < dmain) {
        int2 p = csrp[beg + lane + 64];
        off1 = p.x * NF;
        float2 a = *(const float2*)&as_[p.x * 4 + h0];
        float ww = __int_as_float(p.y);
        float v0 = a.x + ad0 + ww * d0; Lb0 = v0 > 0.f ? v0 : 0.2f * v0;
        float v1 = a.y + ad1 + ww * d1; Lb1 = v1 > 0.f ? v1 : 0.2f * v1;
    }
    float mx0 = fmaxf(La0, Lb0), mx1 = fmaxf(La1, Lb1);
    for (int e = 128 + lane; e < dmain; e += 64) {        // cold: deg > 128
        int2 p = csrp[beg + e];
        float2 a = *(const float2*)&as_[p.x * 4 + h0];
        float ww = __int_as_float(p.y);
        float v0 = a.x + ad0 + ww * d0; v0 = v0 > 0.f ? v0 : 0.2f * v0;
        float v1 = a.y + ad1 + ww * d1; v1 = v1 > 0.f ? v1 : 0.2f * v1;
        mx0 = fmaxf(mx0, v0); mx1 = fmaxf(mx1, v1);
    }
    if (degn > CSTR) {                                    // pathological overflow
        int oc = *ovf_cnt;
        for (int i = lane; i < oc; i += 64) {
            int4 o = ovf[i];
            if (o.x == n) {
                float2 a = *(const float2*)&as_[o.y * 4 + h0];
                float ww = __int_as_float(o.z);
                float v0 = a.x + ad0 + ww * d0; v0 = v0 > 0.f ? v0 : 0.2f * v0;
                float v1 = a.y + ad1 + ww * d1; v1 = v1 > 0.f ? v1 : 0.2f * v1;
                mx0 = fmaxf(mx0, v0); mx1 = fmaxf(mx1, v1);
            }
        }
    }
#pragma unroll
    for (int o = 32; o > 0; o >>= 1) {
        mx0 = fmaxf(mx0, __shfl_xor(mx0, o));
        mx1 = fmaxf(mx1, __shfl_xor(mx1, o));
    }
    float Aa0 = __expf(La0 - mx0), Ab0 = __expf(Lb0 - mx0);
    float Aa1 = __expf(La1 - mx1), Ab1 = __expf(Lb1 - mx1);
    float s0 = Aa0 + Ab0, s1 = Aa1 + Ab1;
    for (int e = 128 + lane; e < dmain; e += 64) {        // cold recompute
        int2 p = csrp[beg + e];
        float2 a = *(const float2*)&as_[p.x * 4 + h0];
        float ww = __int_as_float(p.y);
        float v0 = a.x + ad0 + ww * d0; v0 = v0 > 0.f ? v0 : 0.2f * v0;
        float v1 = a.y + ad1 + ww * d1; v1 = v1 > 0.f ? v1 : 0.2f * v1;
        s0 += __expf(v0 - mx0); s1 += __expf(v1 - mx1);
    }
    if (degn > CSTR) {
        int oc = *ovf_cnt;
        for (int i = lane; i < oc; i += 64) {
            int4 o = ovf[i];
            if (o.x == n) {
                float2 a = *(const float2*)&as_[o.y * 4 + h0];
                float ww = __int_as_float(o.z);
                float v0 = a.x + ad0 + ww * d0; v0 = v0 > 0.f ? v0 : 0.2f * v0;
                float v1 = a.y + ad1 + ww * d1; v1 = v1 > 0.f ? v1 : 0.2f * v1;
                s0 += __expf(v0 - mx0); s1 += __expf(v1 - mx1);
            }
        }
    }
#pragma unroll
    for (int o = 32; o > 0; o >>= 1) {
        s0 += __shfl_xor(s0, o); s1 += __shfl_xor(s1, o);
    }
    float inv0 = 1.f / (s0 + 1e-16f), inv1 = 1.f / (s1 + 1e-16f);
    // ---- phase B: lane owns 4 channels at hp*256 + 4*lane ----
    bool hi = lane >= 32;               // lanes 32-63 hold head 2hp+1
    const ushort* hbase = hb + hp * 256 + 4 * lane;
    float4 acc = make_float4(0.f, 0.f, 0.f, 0.f);
    int m0 = min(dmain, 64);
#pragma unroll 16
    for (int e = 0; e < m0; e++) {
        float al = __shfl(Aa0, e), ah = __shfl(Aa1, e);
        float a = hi ? ah : al;
        int o = __shfl(off0, e);
        uint2 v = *(const uint2*)(hbase + o);             // 512B/wave
        acc.x += a * bflo(v.x); acc.y += a * bfhi(v.x);
        acc.z += a * bflo(v.y); acc.w += a * bfhi(v.y);
    }
    int m1 = min(dmain, 128);
#pragma unroll 16
    for (int e = 64; e < m1; e++) {
        float al = __shfl(Ab0, e - 64), ah = __shfl(Ab1, e - 64);
        float a = hi ? ah : al;
        int o = __shfl(off1, e - 64);
        uint2 v = *(const uint2*)(hbase + o);
        acc.x += a * bflo(v.x); acc.y += a * bfhi(v.x);
        acc.z += a * bflo(v.y); acc.w += a * bfhi(v.y);
    }
    for (int e = 128; e < dmain; e++) {                   // cold: deg > 128
        int2 p = csrp[beg + e];
        float2 aa = *(const float2*)&as_[p.x * 4 + h0];
        float ww = __int_as_float(p.y);
        float v0 = aa.x + ad0 + ww * d0; v0 = v0 > 0.f ? v0 : 0.2f * v0;
        float v1 = aa.y + ad1 + ww * d1; v1 = v1 > 0.f ? v1 : 0.2f * v1;
        float a = hi ? __expf(v1 - mx1) : __expf(v0 - mx0);
        uint2 v = *(const uint2*)(hbase + p.x * NF);
        acc.x += a * bflo(v.x); acc.y += a * bfhi(v.x);
        acc.z += a * bflo(v.y); acc.w += a * bfhi(v.y);
    }
    if (degn > CSTR) {                                    // pathological overflow
        int oc = *ovf_cnt;
        for (int i = 0; i < oc; i++) {
            int4 o = ovf[i];
            if (o.x == n) {
                float2 aa = *(const float2*)&as_[o.y * 4 + h0];
                float ww = __int_as_float(o.z);
                float v0 = aa.x + ad0 + ww * d0; v0 = v0 > 0.f ? v0 : 0.2f * v0;
                float v1 = aa.y + ad1 + ww * d1; v1 = v1 > 0.f ? v1 : 0.2f * v1;
                float a = hi ? __expf(v1 - mx1) : __expf(v0 - mx0);
                uint2 v = *(const uint2*)(hbase + o.y * NF);
                acc.x += a * bflo(v.x); acc.y += a * bfhi(v.x);
                acc.z += a * bflo(v.y); acc.w += a * bfhi(v.y);
            }
        }
    }
    float inv = hi ? inv1 : inv0;
    int ch = hp * 256 + 4 * lane;
    float4 b4 = *(const float4*)&bias[ch];
    ushort4 o4;
    o4.x = f2bf(acc.x * inv + b4.x); o4.y = f2bf(acc.y * inv + b4.y);
    o4.z = f2bf(acc.z * inv + b4.z); o4.w = f2bf(acc.w * inv + b4.w);
    *(ushort4*)&outb[n * NF + ch] = o4;
}

// ---------------- kernel 3: BN stats from bf16 (160 blocks) ---------------
__global__ void k_bnstats(const ushort* __restrict__ x, float* __restrict__ stats) {
    int t = threadIdx.x;
    int r0 = blockIdx.x * 16;
    float s = 0.f, s2 = 0.f;
    for (int r = r0; r < r0 + 16; r++) {
        float v = bf2f(x[r * NF + t]);
        s += v; s2 += v * v;
    }
    atomicAdd(&stats[t], s);
    atomicAdd(&stats[NF + t], s2);
}

// ---------------- kernel 4: GEMM2 MFMA + inline BN1+relu + node-att -------
// 64x128 tiles -> 160 blocks; A operand bf16 (t1b).
__global__ __launch_bounds__(256) void k_gemm2_bn_att(const ushort* __restrict__ Ab,
        const float* __restrict__ stats, const float* __restrict__ g,
        const float* __restrict__ bb, const ushort* __restrict__ BT,
        const float* __restrict__ atts, const float* __restrict__ attd,
        ushort* __restrict__ Cb, float* __restrict__ as_, float* __restrict__ ad_) {
    __shared__ ushort As[64][40];    // [m][k], +8 pad
    __shared__ ushort Bs[128][40];   // [n][k], +8 pad
    __shared__ float s_scale[512], s_shift[512];
    __shared__ float s_ps[2][64], s_pd[2][64];
    int t = threadIdx.x;
    const float invn = 1.0f / (float)NN;
    {
        int j = t;
#pragma unroll
        for (int rep = 0; rep < 2; rep++, j += 256) {
            float mu = stats[j] * invn;
            float var = stats[NF + j] * invn - mu * mu;
            float sc = rsqrtf(var + 1e-5f) * g[j];
            s_scale[j] = sc;
            s_shift[j] = bb[j] - mu * sc;
        }
    }
    int head = blockIdx.x;
    int rowBase = blockIdx.y * 64, colBase = head * 128;
    int w = t >> 6, lane = t & 63;
    int wm = (w >> 1) * 32, wn = (w & 1) * 64;
    int lm = lane & 15, q = lane >> 4;
    f32x4 acc[2][4] = {};
    int sr2 = t >> 2, sk = (t & 3) * 8;
    for (int k0 = 0; k0 < 512; k0 += 32) {
        __syncthreads();
        int jb = k0 + sk;
        float sc[8], sh[8];
#pragma unroll
        for (int c = 0; c < 8; c++) { sc[c] = s_scale[jb + c]; sh[c] = s_shift[jb + c]; }
        uint4 a8 = *(const uint4*)&Ab[(rowBase + sr2) * 512 + jb];   // 8 bf16
        uint4 b0 = *(const uint4*)&BT[(colBase + sr2) * 512 + jb];
        uint4 b1 = *(const uint4*)&BT[(colBase + 64 + sr2) * 512 + jb];
        ushort pa0[8];
        float av[8];
        av[0] = bflo(a8.x); av[1] = bfhi(a8.x); av[2] = bflo(a8.y); av[3] = bfhi(a8.y);
        av[4] = bflo(a8.z); av[5] = bfhi(a8.z); av[6] = bflo(a8.w); av[7] = bfhi(a8.w);
#pragma unroll
        for (int c = 0; c < 8; c++)
            pa0[c] = f2bf(fmaxf(av[c] * sc[c] + sh[c], 0.f));
        *(uint4*)&As[sr2][sk]      = *(uint4*)pa0;
        *(uint4*)&Bs[sr2][sk]      = b0;
        *(uint4*)&Bs[64 + sr2][sk] = b1;
        __syncthreads();
        bf16x8 af[2], bf[4];
#pragma unroll
        for (int i = 0; i < 2; i++) af[i] = *(const bf16x8*)&As[wm + i * 16 + lm][q * 8];
#pragma unroll
        for (int j = 0; j < 4; j++) bf[j] = *(const bf16x8*)&Bs[wn + j * 16 + lm][q * 8];
#pragma unroll
        for (int i = 0; i < 2; i++)
#pragma unroll
            for (int j = 0; j < 4; j++)
                acc[i][j] = __builtin_amdgcn_mfma_f32_16x16x32_bf16(af[i], bf[j], acc[i][j], 0, 0, 0);
    }
    // C store (bf16)
#pragma unroll
    for (int i = 0; i < 2; i++) {
        int row = rowBase + wm + i * 16 + q * 4;
#pragma unroll
        for (int j = 0; j < 4; j++) {
            int col = colBase + wn + j * 16 + lm;
#pragma unroll
            for (int r = 0; r < 4; r++)
                Cb[(row + r) * 512 + col] = f2bf(acc[i][j][r]);
        }
    }
    // node-att epilogue: head dot for this block's 64 rows
    float sa[4], da[4];
#pragma unroll
    for (int j = 0; j < 4; j++) {
        int col = colBase + wn + j * 16 + lm;
        sa[j] = atts[col]; da[j] = attd[col];
    }
#pragma unroll
    for (int i = 0; i < 2; i++) {
#pragma unroll
        for (int r = 0; r < 4; r++) {
            float ps = 0.f, pd = 0.f;
#pragma unroll
            for (int j = 0; j < 4; j++) {
                float c = acc[i][j][r];
                ps += c * sa[j]; pd += c * da[j];
            }
#pragma unroll
            for (int o = 1; o < 16; o <<= 1) { ps += __shfl_xor(ps, o); pd += __shfl_xor(pd, o); }
            if (lm == 0) {
                int row = wm + i * 16 + q * 4 + r;
                s_ps[w & 1][row] = ps; s_pd[w & 1][row] = pd;
            }
        }
    }
    __syncthreads();
    if (t < 64) {
        as_[(rowBase + t) * 4 + head] = s_ps[0][t] + s_ps[1][t];
    } else if (t < 128) {
        int row = t - 64;
        ad_[(rowBase + row) * 4 + head] = s_pd[0][row] + s_pd[1][row];
    }
}

// ---------------- kernel 5: FC MFMA + inline BN2+relu + mask + adj --------
// A operand bf16 (t1b layer-2).
__global__ __launch_bounds__(64) void k_fc_bn(const ushort* __restrict__ e2b,
        const float* __restrict__ stats, const float* __restrict__ g,
        const float* __restrict__ bb, const ushort* __restrict__ WfcT,
        const float* __restrict__ bfc, const int* __restrict__ mask,
        const float* __restrict__ adj, float* __restrict__ out) {
    __shared__ float s_scale[512], s_shift[512];
    int lane = threadIdx.x;
    const float invn = 1.0f / (float)NN;
    for (int j = lane; j < 512; j += 64) {
        float mu = stats[j] * invn;
        float var = stats[NF + j] * invn - mu * mu;
        float sc = rsqrtf(var + 1e-5f) * g[j];
        s_scale[j] = sc;
        s_shift[j] = bb[j] - mu * sc;
    }
    __syncthreads();
    int r0 = blockIdx.x * 16;
    int lm = lane & 15, q = lane >> 4;
    f32x4 acc[3] = {};
#pragma unroll
    for (int k0 = 0; k0 < 512; k0 += 32) {
        int jb = k0 + q * 8;
        uint4 a8 = *(const uint4*)&e2b[(r0 + lm) * 512 + jb];
        float av[8];
        av[0] = bflo(a8.x); av[1] = bfhi(a8.x); av[2] = bflo(a8.y); av[3] = bfhi(a8.y);
        av[4] = bflo(a8.z); av[5] = bfhi(a8.z); av[6] = bflo(a8.w); av[7] = bfhi(a8.w);
        ushort pa[8];
#pragma unroll
        for (int c = 0; c < 8; c++)
            pa[c] = f2bf(fmaxf(av[c] * s_scale[jb + c] + s_shift[jb + c], 0.f));
        bf16x8 af = *(const bf16x8*)pa;
#pragma unroll
        for (int jt = 0; jt < 3; jt++) {
            bf16x8 bf = *(const bf16x8*)&WfcT[(jt * 16 + lm) * 512 + k0 + q * 8];
            acc[jt] = __builtin_amdgcn_mfma_f32_16x16x32_bf16(af, bf, acc[jt], 0, 0, 0);
        }
    }
#pragma unroll
    for (int jt = 0; jt < 3; jt++) {
        int col = jt * 16 + lm;
        if (col < OUTE) {
#pragma unroll
            for (int r = 0; r < 4; r++) {
                int n = r0 + q * 4 + r;
                float v = acc[jt][r] + bfc[col];
                v = mask[n] ? v : 0.f;
                out[n * OUTE + col] = v + adj[n * OUTE + col];
            }
        }
    }
}

// ---------------- host side ----------------------------------------------
extern "C" void kernel_launch(void* const* d_in, const int* in_sizes, int n_in,
                              void* d_out, int out_size, void* d_ws, size_t ws_size,
                              hipStream_t stream) {
    const float* x       = (const float*)d_in[0];
    const int*   ei      = (const int*)d_in[1];
    const float* pos     = (const float*)d_in[2];
    const int*   mask    = (const int*)d_in[3];
    const float* adj     = (const float*)d_in[4];
    const float* W1      = (const float*)d_in[5];
    const float* atts1   = (const float*)d_in[6];
    const float* attd1   = (const float*)d_in[7];
    const float* We1     = (const float*)d_in[8];
    const float* atte1   = (const float*)d_in[9];
    const float* bias1   = (const float*)d_in[10];
    const float* g1      = (const float*)d_in[11];
    const float* be1     = (const float*)d_in[12];
    const float* W2      = (const float*)d_in[13];
    const float* atts2   = (const float*)d_in[14];
    const float* attd2   = (const float*)d_in[15];
    const float* We2     = (const float*)d_in[16];
    const float* atte2   = (const float*)d_in[17];
    const float* bias2   = (const float*)d_in[18];
    const float* g2      = (const float*)d_in[19];
    const float* be2     = (const float*)d_in[20];
    const float* Wfc     = (const float*)d_in[21];
    const float* bfc     = (const float*)d_in[22];
    float* out = (float*)d_out;

    // workspace layout (float-element offsets; 16B-aligned blocks)
    char* ws = (char*)d_ws;
    int*    deg     = (int*)(ws);                       // 2560
    int*    ovf_cnt = (int*)(ws + 2560 * 4);            // 1 (pad 16)
    float*  stats   = (float*)(ws + 5120 * 4);          // 2048 (L1:1024, L2:1024)
    // ---- zero region = first 7168 elements ----
    float*  dote    = (float*)(ws + 7168 * 4);          // 8 (pad 16)
    int2*   csrp    = (int2*)(ws + 7184 * 4);           // 2560*256 int2 = 1310720 ints
    int4*   ovf     = (int4*)(ws + 1317904 * 4);        // 163840 int4 = 655360 ints
    float*  as_     = (float*)(ws + 1973264 * 4);       // 10240
    float*  ad_     = (float*)(ws + 1983504 * 4);       // 10240
    ushort* t1b     = (ushort*)(ws + 1993744 * 4);      // 1310720 bf16 = 655360 ints
    ushort* hb      = (ushort*)(ws + 2649104 * 4);      // 1310720 bf16 = 655360 ints
    ushort* W2T     = (ushort*)(ws + 3304464 * 4);      // 262144 bf16 = 131072 ints
    ushort* WfcT    = (ushort*)(ws + 3435536 * 4);      // 24576 bf16 = 12288 ints
    // total ~3.45M ints = ~13.8 MB

    hipMemsetAsync(d_ws, 0, 7168 * 4, stream);

    // CSR fill (single-pass) + weight prep + GEMM1+att
    k_csr_gemm1<<<802 + NN / 8, 256, 0, stream>>>(ei, pos, deg, csrp, ovf_cnt, ovf,
                                                  We1, atte1, We2, atte2, dote,
                                                  Wfc, WfcT, W2, W2T,
                                                  x, W1, atts1, attd1, hb, as_, ad_);

    // ---- layer 1 ----
    k_edge_agg<<<NN / 2, 256, 0, stream>>>(deg, csrp, ovf_cnt, ovf, as_, ad_,
                                           dote, hb, bias1, t1b);
    k_bnstats<<<NN / 16, 512, 0, stream>>>(t1b, stats);

    // ---- layer 2 (BN1 inline in GEMM2 A-staging; node-att in epilogue) ----
    k_gemm2_bn_att<<<dim3(4, NN / 64), 256, 0, stream>>>(t1b, stats, g1, be1, W2T,
                                                         atts2, attd2, hb, as_, ad_);
    k_edge_agg<<<NN / 2, 256, 0, stream>>>(deg, csrp, ovf_cnt, ovf, as_, ad_,
                                           dote + 4, hb, bias2, t1b);
    k_bnstats<<<NN / 16, 512, 0, stream>>>(t1b, stats + 1024);

    // ---- head (BN2 inline in FC A-fragment load) ----
    k_fc_bn<<<NN / 16, 64, 0, stream>>>(t1b, stats + 1024, g2, be2, WfcT, bfc, mask, adj, out);
}

// Round 21
// 207.677 us; speedup vs baseline: 1.0380x; 1.0380x over previous
//
#include <hip/hip_runtime.h>
#include <hip/hip_bf16.h>

#define NN 2560        // nodes
#define NE 163840      // edges
#define NH 4           // heads
#define NC 128         // channels per head
#define NF 512         // NH*NC
#define OUTE 40
#define CSTR 256       // fixed CSR stride per node; deg>CSTR -> overflow list

typedef short bf16x8 __attribute__((ext_vector_type(8)));
typedef float f32x4 __attribute__((ext_vector_type(4)));

__device__ inline ushort f2bf(float f) {
    uint u = __float_as_uint(f);
    uint r = u + 0x7FFF + ((u >> 16) & 1);   // round-to-nearest-even
    return (ushort)(r >> 16);
}
__device__ inline float bflo(uint v) { return __uint_as_float(v << 16); }
__device__ inline float bfhi(uint v) { return __uint_as_float(v & 0xFFFF0000u); }
__device__ inline float bf2f(ushort u) { return __uint_as_float(((uint)u) << 16); }

// ---------------- kernel 1: CSR fill (single-pass) + dote/WfcT/W2T + GEMM1+att
// blocks 0..639: CSR fill; 640..641: dote; 642..737: WfcT; 738..801: W2T;
// 802..1441: gemm1 + node-att for 4 nodes each (R20's 8-node variant starved
// TLP at 1.25 waves/SIMD — reverted per R10/R12 occupancy law).
__global__ __launch_bounds__(256) void k_csr_gemm1(const int* __restrict__ ei,
        const float* __restrict__ pos, int* __restrict__ deg,
        int2* __restrict__ csrp, int* __restrict__ ovf_cnt, int4* __restrict__ ovf,
        const float* __restrict__ We1, const float* __restrict__ ae1,
        const float* __restrict__ We2, const float* __restrict__ ae2,
        float* __restrict__ dote,
        const float* __restrict__ Wfc, ushort* __restrict__ WfcT,
        const float* __restrict__ W2, ushort* __restrict__ W2T,
        const float* __restrict__ x, const float* __restrict__ W1,
        const float* __restrict__ atts, const float* __restrict__ attd,
        ushort* __restrict__ hb, float* __restrict__ as_, float* __restrict__ ad_) {
    __shared__ ushort tile[64][72];
    __shared__ float s_x[4][32];
    __shared__ float4 s_red[4][4];     // [wave][node]
    int b = blockIdx.x;
    if (b < 640) {
        int e = b * 256 + threadIdx.x;
        int s = ei[e], d = ei[NE + e];
        float dx = pos[2 * s] - pos[2 * d];
        float dy = pos[2 * s + 1] - pos[2 * d + 1];
        float w = 1.0f / (sqrtf(dx * dx + dy * dy) + 1e-6f);
        int r = atomicAdd(&deg[d], 1);     // slot + degree in one pass
        if (r < CSTR) {
            csrp[(d << 8) + r] = make_int2(s, __float_as_int(w));
        } else {                            // pathological deg > CSTR: exact fallback
            int i = atomicAdd(ovf_cnt, 1);
            ovf[i] = make_int4(d, s, __float_as_int(w), 0);
        }
        return;
    }
    if (b < 642) {
        int t = threadIdx.x;
        const float* W = (b == 641) ? We2 : We1;
        const float* A = (b == 641) ? ae2 : ae1;
        int w = t >> 6, l = t & 63;
        float p = W[w * 128 + l] * A[w * 128 + l] + W[w * 128 + 64 + l] * A[w * 128 + 64 + l];
#pragma unroll
        for (int o = 32; o > 0; o >>= 1) p += __shfl_down(p, o);
        if (l == 0) dote[(b - 640) * 4 + w] = p;
        return;
    }
    if (b < 738) {
        int idx = (b - 642) * 256 + threadIdx.x;    // j*512 + k
        int j = idx >> 9, k = idx & 511;
        WfcT[idx] = (j < OUTE) ? f2bf(Wfc[k * OUTE + j]) : (ushort)0;
        return;
    }
    if (b < 802) {
        int id = b - 738;
        int n0 = (id & 7) * 64, k0 = (id >> 3) * 64;
        int t = threadIdx.x;
        int r = t >> 2, cseg = (t & 3) * 16;
#pragma unroll
        for (int c = 0; c < 16; c += 4) {
            float4 v = *(const float4*)&W2[(k0 + r) * 512 + n0 + cseg + c];
            tile[cseg + c + 0][r] = f2bf(v.x);
            tile[cseg + c + 1][r] = f2bf(v.y);
            tile[cseg + c + 2][r] = f2bf(v.z);
            tile[cseg + c + 3][r] = f2bf(v.w);
        }
        __syncthreads();
        *(uint4*)&W2T[(n0 + r) * 512 + k0 + cseg]     = *(uint4*)&tile[r][cseg];
        *(uint4*)&W2T[(n0 + r) * 512 + k0 + cseg + 8] = *(uint4*)&tile[r][cseg + 8];
        return;
    }
    int n0 = (b - 802) * 4, t = threadIdx.x;
    if (t < 128) s_x[t >> 5][t & 31] = x[n0 * 32 + t];
    __syncthreads();
    float a0[4] = {0.f, 0.f, 0.f, 0.f}, a1[4] = {0.f, 0.f, 0.f, 0.f};
#pragma unroll
    for (int k = 0; k < 32; k++) {
        float w0 = W1[k * 512 + t];
        float w1 = W1[k * 512 + t + 256];
#pragma unroll
        for (int nn = 0; nn < 4; nn++) {
            a0[nn] += s_x[nn][k] * w0;
            a1[nn] += s_x[nn][k] * w1;
        }
    }
    float sa0 = atts[t], sa1 = atts[t + 256];
    float da0 = attd[t], da1 = attd[t + 256];
    int w = t >> 6, lane = t & 63;
#pragma unroll
    for (int nn = 0; nn < 4; nn++) {
        hb[(n0 + nn) * 512 + t] = f2bf(a0[nn]);
        hb[(n0 + nn) * 512 + t + 256] = f2bf(a1[nn]);
        float ps0 = a0[nn] * sa0, pd0 = a0[nn] * da0;
        float ps1 = a1[nn] * sa1, pd1 = a1[nn] * da1;
#pragma unroll
        for (int o = 32; o > 0; o >>= 1) {
            ps0 += __shfl_xor(ps0, o); pd0 += __shfl_xor(pd0, o);
            ps1 += __shfl_xor(ps1, o); pd1 += __shfl_xor(pd1, o);
        }
        if (lane == 0) s_red[w][nn] = make_float4(ps0, pd0, ps1, pd1);
    }
    __syncthreads();
    if (t < 4) {
        int nn = t, n = n0 + nn;
        float4 r0 = s_red[0][nn], r1 = s_red[1][nn], r2 = s_red[2][nn], r3 = s_red[3][nn];
        as_[n * 4 + 0] = r0.x + r1.x; as_[n * 4 + 1] = r2.x + r3.x;
        as_[n * 4 + 2] = r0.z + r1.z; as_[n * 4 + 3] = r2.z + r3.z;
        ad_[n * 4 + 0] = r0.y + r1.y; ad_[n * 4 + 1] = r2.y + r3.y;
        ad_[n * 4 + 2] = r0.w + r1.w; ad_[n * 4 + 3] = r2.w + r3.w;
    }
}

// ---------------- kernel 2: softmax+agg, wave = (node, head-pair) ---------
// Zero LDS, zero barriers (R15 structure). Output bf16 (t1b).
__global__ __launch_bounds__(256) void k_edge_agg(const int* __restrict__ deg_,
        const int2* __restrict__ csrp, const int* __restrict__ ovf_cnt,
        const int4* __restrict__ ovf, const float* __restrict__ as_,
        const float* __restrict__ ad_, const float* __restrict__ dote,
        const ushort* __restrict__ hb, const float* __restrict__ bias,
        ushort* __restrict__ outb) {
    int w = threadIdx.x >> 6, lane = threadIdx.x & 63;
    int n = blockIdx.x * 2 + (w >> 1);
    int hp = w & 1;                     // heads 2hp, 2hp+1
    int h0 = 2 * hp;
    int beg = n << 8;
    int degn = deg_[n];
    int dmain = min(degn, CSTR);
    float ad0 = ad_[n * 4 + h0], ad1 = ad_[n * 4 + h0 + 1];
    float d0 = dote[h0], d1 = dote[h0 + 1];
    // ---- phase A: softmax for both heads in registers ----
    float La0 = -1e30f, La1 = -1e30f, Lb0 = -1e30f, Lb1 = -1e30f;
    int off0 = 0, off1 = 0;
    if (lane < dmain) {
        int2 p = csrp[beg + lane];
        off0 = p.x * NF;
        float2 a = *(const float2*)&as_[p.x * 4 + h0];
        float ww = __int_as_float(p.y);
        float v0 = a.x + ad0 + ww * d0; La0 = v0 > 0.f ? v0 : 0.2f * v0;
        float v1 = a.y + ad1 + ww * d1; La1 = v1 > 0.f ? v1 : 0.2f * v1;
    }
    if (lane + 64 < dmain) {
        int2 p = csrp[beg + lane + 64];
        off1 = p.x * NF;
        float2 a = *(const float2*)&as_[p.x * 4 + h0];
        float ww = __int_as_float(p.y);
        float v0 = a.x + ad0 + ww * d0; Lb0 = v0 > 0.f ? v0 : 0.2f * v0;
        float v1 = a.y + ad1 + ww * d1; Lb1 = v1 > 0.f ? v1 : 0.2f * v1;
    }
    float mx0 = fmaxf(La0, Lb0), mx1 = fmaxf(La1, Lb1);
    for (int e = 128 + lane; e < dmain; e += 64) {        // cold: deg > 128
        int2 p = csrp[beg + e];
        float2 a = *(const float2*)&as_[p.x * 4 + h0];
        float ww = __int_as_float(p.y);
        float v0 = a.x + ad0 + ww * d0; v0 = v0 > 0.f ? v0 : 0.2f * v0;
        float v1 = a.y + ad1 + ww * d1; v1 = v1 > 0.f ? v1 : 0.2f * v1;
        mx0 = fmaxf(mx0, v0); mx1 = fmaxf(mx1, v1);
    }
    if (degn > CSTR) {                                    // pathological overflow
        int oc = *ovf_cnt;
        for (int i = lane; i < oc; i += 64) {
            int4 o = ovf[i];
            if (o.x == n) {
                float2 a = *(const float2*)&as_[o.y * 4 + h0];
                float ww = __int_as_float(o.z);
                float v0 = a.x + ad0 + ww * d0; v0 = v0 > 0.f ? v0 : 0.2f * v0;
                float v1 = a.y + ad1 + ww * d1; v1 = v1 > 0.f ? v1 : 0.2f * v1;
                mx0 = fmaxf(mx0, v0); mx1 = fmaxf(mx1, v1);
            }
        }
    }
#pragma unroll
    for (int o = 32; o > 0; o >>= 1) {
        mx0 = fmaxf(mx0, __shfl_xor(mx0, o));
        mx1 = fmaxf(mx1, __shfl_xor(mx1, o));
    }
    float Aa0 = __expf(La0 - mx0), Ab0 = __expf(Lb0 - mx0);
    float Aa1 = __expf(La1 - mx1), Ab1 = __expf(Lb1 - mx1);
    float s0 = Aa0 + Ab0, s1 = Aa1 + Ab1;
    for (int e = 128 + lane; e < dmain; e += 64) {        // cold recompute
        int2 p = csrp[beg + e];
        float2 a = *(const float2*)&as_[p.x * 4 + h0];
        float ww = __int_as_float(p.y);
        float v0 = a.x + ad0 + ww * d0; v0 = v0 > 0.f ? v0 : 0.2f * v0;
        float v1 = a.y + ad1 + ww * d1; v1 = v1 > 0.f ? v1 : 0.2f * v1;
        s0 += __expf(v0 - mx0); s1 += __expf(v1 - mx1);
    }
    if (degn > CSTR) {
        int oc = *ovf_cnt;
        for (int i = lane; i < oc; i += 64) {
            int4 o = ovf[i];
            if (o.x == n) {
                float2 a = *(const float2*)&as_[o.y * 4 + h0];
                float ww = __int_as_float(o.z);
                float v0 = a.x + ad0 + ww * d0; v0 = v0 > 0.f ? v0 : 0.2f * v0;
                float v1 = a.y + ad1 + ww * d1; v1 = v1 > 0.f ? v1 : 0.2f * v1;
                s0 += __expf(v0 - mx0); s1 += __expf(v1 - mx1);
            }
        }
    }
#pragma unroll
    for (int o = 32; o > 0; o >>= 1) {
        s0 += __shfl_xor(s0, o); s1 += __shfl_xor(s1, o);
    }
    float inv0 = 1.f / (s0 + 1e-16f), inv1 = 1.f / (s1 + 1e-16f);
    // ---- phase B: lane owns 4 channels at hp*256 + 4*lane ----
    bool hi = lane >= 32;               // lanes 32-63 hold head 2hp+1
    const ushort* hbase = hb + hp * 256 + 4 * lane;
    float4 acc = make_float4(0.f, 0.f, 0.f, 0.f);
    int m0 = min(dmain, 64);
#pragma unroll 16
    for (int e = 0; e < m0; e++) {
        float al = __shfl(Aa0, e), ah = __shfl(Aa1, e);
        float a = hi ? ah : al;
        int o = __shfl(off0, e);
        uint2 v = *(const uint2*)(hbase + o);             // 512B/wave
        acc.x += a * bflo(v.x); acc.y += a * bfhi(v.x);
        acc.z += a * bflo(v.y); acc.w += a * bfhi(v.y);
    }
    int m1 = min(dmain, 128);
#pragma unroll 16
    for (int e = 64; e < m1; e++) {
        float al = __shfl(Ab0, e - 64), ah = __shfl(Ab1, e - 64);
        float a = hi ? ah : al;
        int o = __shfl(off1, e - 64);
        uint2 v = *(const uint2*)(hbase + o);
        acc.x += a * bflo(v.x); acc.y += a * bfhi(v.x);
        acc.z += a * bflo(v.y); acc.w += a * bfhi(v.y);
    }
    for (int e = 128; e < dmain; e++) {                   // cold: deg > 128
        int2 p = csrp[beg + e];
        float2 aa = *(const float2*)&as_[p.x * 4 + h0];
        float ww = __int_as_float(p.y);
        float v0 = aa.x + ad0 + ww * d0; v0 = v0 > 0.f ? v0 : 0.2f * v0;
        float v1 = aa.y + ad1 + ww * d1; v1 = v1 > 0.f ? v1 : 0.2f * v1;
        float a = hi ? __expf(v1 - mx1) : __expf(v0 - mx0);
        uint2 v = *(const uint2*)(hbase + p.x * NF);
        acc.x += a * bflo(v.x); acc.y += a * bfhi(v.x);
        acc.z += a * bflo(v.y); acc.w += a * bfhi(v.y);
    }
    if (degn > CSTR) {                                    // pathological overflow
        int oc = *ovf_cnt;
        for (int i = 0; i < oc; i++) {
            int4 o = ovf[i];
            if (o.x == n) {
                float2 aa = *(const float2*)&as_[o.y * 4 + h0];
                float ww = __int_as_float(o.z);
                float v0 = aa.x + ad0 + ww * d0; v0 = v0 > 0.f ? v0 : 0.2f * v0;
                float v1 = aa.y + ad1 + ww * d1; v1 = v1 > 0.f ? v1 : 0.2f * v1;
                float a = hi ? __expf(v1 - mx1) : __expf(v0 - mx0);
                uint2 v = *(const uint2*)(hbase + o.y * NF);
                acc.x += a * bflo(v.x); acc.y += a * bfhi(v.x);
                acc.z += a * bflo(v.y); acc.w += a * bfhi(v.y);
            }
        }
    }
    float inv = hi ? inv1 : inv0;
    int ch = hp * 256 + 4 * lane;
    float4 b4 = *(const float4*)&bias[ch];
    ushort4 o4;
    o4.x = f2bf(acc.x * inv + b4.x); o4.y = f2bf(acc.y * inv + b4.y);
    o4.z = f2bf(acc.z * inv + b4.z); o4.w = f2bf(acc.w * inv + b4.w);
    *(ushort4*)&outb[n * NF + ch] = o4;
}

// ---------------- kernel 3: BN stats from bf16 (160 blocks) ---------------
__global__ void k_bnstats(const ushort* __restrict__ x, float* __restrict__ stats) {
    int t = threadIdx.x;
    int r0 = blockIdx.x * 16;
    float s = 0.f, s2 = 0.f;
    for (int r = r0; r < r0 + 16; r++) {
        float v = bf2f(x[r * NF + t]);
        s += v; s2 += v * v;
    }
    atomicAdd(&stats[t], s);
    atomicAdd(&stats[NF + t], s2);
}

// ---------------- kernel 4: GEMM2 MFMA + inline BN1+relu + node-att -------
// 64x128 tiles -> 160 blocks; A operand bf16 (t1b).
__global__ __launch_bounds__(256) void k_gemm2_bn_att(const ushort* __restrict__ Ab,
        const float* __restrict__ stats, const float* __restrict__ g,
        const float* __restrict__ bb, const ushort* __restrict__ BT,
        const float* __restrict__ atts, const float* __restrict__ attd,
        ushort* __restrict__ Cb, float* __restrict__ as_, float* __restrict__ ad_) {
    __shared__ ushort As[64][40];    // [m][k], +8 pad
    __shared__ ushort Bs[128][40];   // [n][k], +8 pad
    __shared__ float s_scale[512], s_shift[512];
    __shared__ float s_ps[2][64], s_pd[2][64];
    int t = threadIdx.x;
    const float invn = 1.0f / (float)NN;
    {
        int j = t;
#pragma unroll
        for (int rep = 0; rep < 2; rep++, j += 256) {
            float mu = stats[j] * invn;
            float var = stats[NF + j] * invn - mu * mu;
            float sc = rsqrtf(var + 1e-5f) * g[j];
            s_scale[j] = sc;
            s_shift[j] = bb[j] - mu * sc;
        }
    }
    int head = blockIdx.x;
    int rowBase = blockIdx.y * 64, colBase = head * 128;
    int w = t >> 6, lane = t & 63;
    int wm = (w >> 1) * 32, wn = (w & 1) * 64;
    int lm = lane & 15, q = lane >> 4;
    f32x4 acc[2][4] = {};
    int sr2 = t >> 2, sk = (t & 3) * 8;
    for (int k0 = 0; k0 < 512; k0 += 32) {
        __syncthreads();
        int jb = k0 + sk;
        float sc[8], sh[8];
#pragma unroll
        for (int c = 0; c < 8; c++) { sc[c] = s_scale[jb + c]; sh[c] = s_shift[jb + c]; }
        uint4 a8 = *(const uint4*)&Ab[(rowBase + sr2) * 512 + jb];   // 8 bf16
        uint4 b0 = *(const uint4*)&BT[(colBase + sr2) * 512 + jb];
        uint4 b1 = *(const uint4*)&BT[(colBase + 64 + sr2) * 512 + jb];
        ushort pa0[8];
        float av[8];
        av[0] = bflo(a8.x); av[1] = bfhi(a8.x); av[2] = bflo(a8.y); av[3] = bfhi(a8.y);
        av[4] = bflo(a8.z); av[5] = bfhi(a8.z); av[6] = bflo(a8.w); av[7] = bfhi(a8.w);
#pragma unroll
        for (int c = 0; c < 8; c++)
            pa0[c] = f2bf(fmaxf(av[c] * sc[c] + sh[c], 0.f));
        *(uint4*)&As[sr2][sk]      = *(uint4*)pa0;
        *(uint4*)&Bs[sr2][sk]      = b0;
        *(uint4*)&Bs[64 + sr2][sk] = b1;
        __syncthreads();
        bf16x8 af[2], bf[4];
#pragma unroll
        for (int i = 0; i < 2; i++) af[i] = *(const bf16x8*)&As[wm + i * 16 + lm][q * 8];
#pragma unroll
        for (int j = 0; j < 4; j++) bf[j] = *(const bf16x8*)&Bs[wn + j * 16 + lm][q * 8];
#pragma unroll
        for (int i = 0; i < 2; i++)
#pragma unroll
            for (int j = 0; j < 4; j++)
                acc[i][j] = __builtin_amdgcn_mfma_f32_16x16x32_bf16(af[i], bf[j], acc[i][j], 0, 0, 0);
    }
    // C store (bf16)
#pragma unroll
    for (int i = 0; i < 2; i++) {
        int row = rowBase + wm + i * 16 + q * 4;
#pragma unroll
        for (int j = 0; j < 4; j++) {
            int col = colBase + wn + j * 16 + lm;
#pragma unroll
            for (int r = 0; r < 4; r++)
                Cb[(row + r) * 512 + col] = f2bf(acc[i][j][r]);
        }
    }
    // node-att epilogue: head dot for this block's 64 rows
    float sa[4], da[4];
#pragma unroll
    for (int j = 0; j < 4; j++) {
        int col = colBase + wn + j * 16 + lm;
        sa[j] = atts[col]; da[j] = attd[col];
    }
#pragma unroll
    for (int i = 0; i < 2; i++) {
#pragma unroll
        for (int r = 0; r < 4; r++) {
            float ps = 0.f, pd = 0.f;
#pragma unroll
            for (int j = 0; j < 4; j++) {
                float c = acc[i][j][r];
                ps += c * sa[j]; pd += c * da[j];
            }
#pragma unroll
            for (int o = 1; o < 16; o <<= 1) { ps += __shfl_xor(ps, o); pd += __shfl_xor(pd, o); }
            if (lm == 0) {
                int row = wm + i * 16 + q * 4 + r;
                s_ps[w & 1][row] = ps; s_pd[w & 1][row] = pd;
            }
        }
    }
    __syncthreads();
    if (t < 64) {
        as_[(rowBase + t) * 4 + head] = s_ps[0][t] + s_ps[1][t];
    } else if (t < 128) {
        int row = t - 64;
        ad_[(rowBase + row) * 4 + head] = s_pd[0][row] + s_pd[1][row];
    }
}

// ---------------- kernel 5: FC MFMA + inline BN2+relu + mask + adj --------
// A operand bf16 (t1b layer-2).
__global__ __launch_bounds__(64) void k_fc_bn(const ushort* __restrict__ e2b,
        const float* __restrict__ stats, const float* __restrict__ g,
        const float* __restrict__ bb, const ushort* __restrict__ WfcT,
        const float* __restrict__ bfc, const int* __restrict__ mask,
        const float* __restrict__ adj, float* __restrict__ out) {
    __shared__ float s_scale[512], s_shift[512];
    int lane = threadIdx.x;
    const float invn = 1.0f / (float)NN;
    for (int j = lane; j < 512; j += 64) {
        float mu = stats[j] * invn;
        float var = stats[NF + j] * invn - mu * mu;
        float sc = rsqrtf(var + 1e-5f) * g[j];
        s_scale[j] = sc;
        s_shift[j] = bb[j] - mu * sc;
    }
    __syncthreads();
    int r0 = blockIdx.x * 16;
    int lm = lane & 15, q = lane >> 4;
    f32x4 acc[3] = {};
#pragma unroll
    for (int k0 = 0; k0 < 512; k0 += 32) {
        int jb = k0 + q * 8;
        uint4 a8 = *(const uint4*)&e2b[(r0 + lm) * 512 + jb];
        float av[8];
        av[0] = bflo(a8.x); av[1] = bfhi(a8.x); av[2] = bflo(a8.y); av[3] = bfhi(a8.y);
        av[4] = bflo(a8.z); av[5] = bfhi(a8.z); av[6] = bflo(a8.w); av[7] = bfhi(a8.w);
        ushort pa[8];
#pragma unroll
        for (int c = 0; c < 8; c++)
            pa[c] = f2bf(fmaxf(av[c] * s_scale[jb + c] + s_shift[jb + c], 0.f));
        bf16x8 af = *(const bf16x8*)pa;
#pragma unroll
        for (int jt = 0; jt < 3; jt++) {
            bf16x8 bf = *(const bf16x8*)&WfcT[(jt * 16 + lm) * 512 + k0 + q * 8];
            acc[jt] = __builtin_amdgcn_mfma_f32_16x16x32_bf16(af, bf, acc[jt], 0, 0, 0);
        }
    }
#pragma unroll
    for (int jt = 0; jt < 3; jt++) {
        int col = jt * 16 + lm;
        if (col < OUTE) {
#pragma unroll
            for (int r = 0; r < 4; r++) {
                int n = r0 + q * 4 + r;
                float v = acc[jt][r] + bfc[col];
                v = mask[n] ? v : 0.f;
                out[n * OUTE + col] = v + adj[n * OUTE + col];
            }
        }
    }
}

// ---------------- host side ----------------------------------------------
extern "C" void kernel_launch(void* const* d_in, const int* in_sizes, int n_in,
                              void* d_out, int out_size, void* d_ws, size_t ws_size,
                              hipStream_t stream) {
    const float* x       = (const float*)d_in[0];
    const int*   ei      = (const int*)d_in[1];
    const float* pos     = (const float*)d_in[2];
    const int*   mask    = (const int*)d_in[3];
    const float* adj     = (const float*)d_in[4];
    const float* W1      = (const float*)d_in[5];
    const float* atts1   = (const float*)d_in[6];
    const float* attd1   = (const float*)d_in[7];
    const float* We1     = (const float*)d_in[8];
    const float* atte1   = (const float*)d_in[9];
    const float* bias1   = (const float*)d_in[10];
    const float* g1      = (const float*)d_in[11];
    const float* be1     = (const float*)d_in[12];
    const float* W2      = (const float*)d_in[13];
    const float* atts2   = (const float*)d_in[14];
    const float* attd2   = (const float*)d_in[15];
    const float* We2     = (const float*)d_in[16];
    const float* atte2   = (const float*)d_in[17];
    const float* bias2   = (const float*)d_in[18];
    const float* g2      = (const float*)d_in[19];
    const float* be2     = (const float*)d_in[20];
    const float* Wfc     = (const float*)d_in[21];
    const float* bfc     = (const float*)d_in[22];
    float* out = (float*)d_out;

    // workspace layout (float-element offsets; 16B-aligned blocks)
    char* ws = (char*)d_ws;
    int*    deg     = (int*)(ws);                       // 2560
    int*    ovf_cnt = (int*)(ws + 2560 * 4);            // 1 (pad 16)
    float*  stats   = (float*)(ws + 5120 * 4);          // 2048 (L1:1024, L2:1024)
    // ---- zero region = first 7168 elements ----
    float*  dote    = (float*)(ws + 7168 * 4);          // 8 (pad 16)
    int2*   csrp    = (int2*)(ws + 7184 * 4);           // 2560*256 int2 = 1310720 ints
    int4*   ovf     = (int4*)(ws + 1317904 * 4);        // 163840 int4 = 655360 ints
    float*  as_     = (float*)(ws + 1973264 * 4);       // 10240
    float*  ad_     = (float*)(ws + 1983504 * 4);       // 10240
    ushort* t1b     = (ushort*)(ws + 1993744 * 4);      // 1310720 bf16 = 655360 ints
    ushort* hb      = (ushort*)(ws + 2649104 * 4);      // 1310720 bf16 = 655360 ints
    ushort* W2T     = (ushort*)(ws + 3304464 * 4);      // 262144 bf16 = 131072 ints
    ushort* WfcT    = (ushort*)(ws + 3435536 * 4);      // 24576 bf16 = 12288 ints
    // total ~3.45M ints = ~13.8 MB

    hipMemsetAsync(d_ws, 0, 7168 * 4, stream);

    // CSR fill (single-pass) + weight prep + GEMM1+att (4 nodes/block)
    k_csr_gemm1<<<802 + NN / 4, 256, 0, stream>>>(ei, pos, deg, csrp, ovf_cnt, ovf,
                                                  We1, atte1, We2, atte2, dote,
                                                  Wfc, WfcT, W2, W2T,
                                                  x, W1, atts1, attd1, hb, as_, ad_);

    // ---- layer 1 ----
    k_edge_agg<<<NN / 2, 256, 0, stream>>>(deg, csrp, ovf_cnt, ovf, as_, ad_,
                                           dote, hb, bias1, t1b);
    k_bnstats<<<NN / 16, 512, 0, stream>>>(t1b, stats);

    // ---- layer 2 (BN1 inline in GEMM2 A-staging; node-att in epilogue) ----
    k_gemm2_bn_att<<<dim3(4, NN / 64), 256, 0, stream>>>(t1b, stats, g1, be1, W2T,
                                                         atts2, attd2, hb, as_, ad_);
    k_edge_agg<<<NN / 2, 256, 0, stream>>>(deg, csrp, ovf_cnt, ovf, as_, ad_,
                                           dote + 4, hb, bias2, t1b);
    k_bnstats<<<NN / 16, 512, 0, stream>>>(t1b, stats + 1024);

    // ---- head (BN2 inline in FC A-fragment load) ----
    k_fc_bn<<<NN / 16, 64, 0, stream>>>(t1b, stats + 1024, g2, be2, WfcT, bfc, mask, adj, out);
}